// Round 2
// baseline (404.758 us; speedup 1.0000x reference)
//
#include <hip/hip_runtime.h>
#include <math.h>

// Problem constants (fixed by setup_inputs)
#define BATCH 32768
#define SS 16          // bands / sequence
#define DI 14          // input dim
#define BQ 256         // stored patterns
#define NC 7           // classes
#define ROWS (BATCH * SS)   // 524288 (b,s) rows
#define BLOCKS 1024         // 512 rows per 256-thread block (2 rows per lane)

// fp32 top-2 gap below which we re-run the row's argmax in fp64.
// Worst-case fp32 dot error ~3e-5 (14-term FMA chain + fp32 LN); 10x safety.
#define MARGIN 3.0e-4f

// ws layout
#define WS_KP64_OFF 0                         // double2[256][7]  (28672 B) k fp64, per-pattern rows
#define WS_KF32_OFF 28672                     // float [256][16]  (16384 B) k fp32, padded to 16
#define WS_TF_OFF   (28672 + 16384)           // float [256][7]   ( 7168 B) per-pattern class table
#define WS_ZB_OFF   (28672 + 16384 + 7168)    // float [7]        head bias: bm*sum(Wb)+bb

__global__ __launch_bounds__(256) void precompute_kernel(
    const float* __restrict__ lookup,
    const float* __restrict__ g_st, const float* __restrict__ b_st,
    const float* __restrict__ g_pp, const float* __restrict__ b_pp,
    const float* __restrict__ Wv,  const float* __restrict__ Wo,
    const float* __restrict__ Wm,  const float* __restrict__ bm,
    const float* __restrict__ Wb,  const float* __restrict__ bb,
    double2* __restrict__ kp64, float* __restrict__ kf32,
    float* __restrict__ Tf, float* __restrict__ zbf)
{
    __shared__ double G1s[256][7];   // (Wo.T @ Wm.T)  : [p][c]
    __shared__ double Gs[14][7];     // Wv.T @ G1      : [d][c]
    const int tid = threadIdx.x;

    // G1[p][c] = sum_o Wo[o,p] * Wm[c,o]
    {
        const int p = tid;
        for (int c = 0; c < NC; ++c) {
            double acc = 0.0;
            for (int o = 0; o < 28; ++o)
                acc += (double)Wo[o * 256 + p] * (double)Wm[c * 28 + o];
            G1s[p][c] = acc;
        }
    }
    __syncthreads();
    // G[d][c] = sum_p Wv[p,d] * G1[p][c]
    if (tid < DI * NC) {
        const int d = tid / NC, c = tid % NC;
        double acc = 0.0;
        for (int p = 0; p < 256; ++p)
            acc += (double)Wv[p * DI + d] * G1s[p][c];
        Gs[d][c] = acc;
    }
    __syncthreads();

    // Per stored pattern j: LayerNorm once in fp64, emit k (f64 + f32) and T row.
    {
        const int j = tid;
        double xr[DI];
        double sum = 0.0;
        for (int d = 0; d < DI; ++d) { xr[d] = (double)lookup[j * DI + d]; sum += xr[d]; }
        const double mu = sum * (1.0 / (double)DI);
        double vs = 0.0;
        for (int d = 0; d < DI; ++d) { const double t = xr[d] - mu; vs += t * t; }
        const double rs = 1.0 / sqrt(vs * (1.0 / (double)DI) + 1e-5);

        double kj[DI], vl[DI];
        for (int d = 0; d < DI; ++d) {
            const double nrm = (xr[d] - mu) * rs;
            kj[d] = nrm * (double)g_st[d] + (double)b_st[d];
            vl[d] = nrm * (double)g_pp[d] + (double)b_pp[d];
        }
        for (int d2 = 0; d2 < DI / 2; ++d2) {
            double2 kv; kv.x = kj[2 * d2]; kv.y = kj[2 * d2 + 1];
            kp64[j * 7 + d2] = kv;
        }
        for (int d = 0; d < DI; ++d) kf32[j * 16 + d] = (float)kj[d];
        kf32[j * 16 + 14] = 0.0f;
        kf32[j * 16 + 15] = 0.0f;
        for (int c = 0; c < NC; ++c) {
            double acc = 0.0;
            for (int d = 0; d < DI; ++d) acc += vl[d] * Gs[d][c];
            Tf[j * NC + c] = (float)acc;
        }
    }
    if (tid < NC) {
        double wbsum = 0.0;
        for (int s = 0; s < SS; ++s) wbsum += (double)Wb[s];
        zbf[tid] = (float)((double)bm[tid] * wbsum + (double)bb[0]);
    }
}

// Cold path: exact fp64 argmax for one row (called for ~1e-4 of rows).
__device__ __noinline__ int refine_row(const float* __restrict__ xrow,
                                       const double2* __restrict__ kp64,
                                       const float* __restrict__ g_sp,
                                       const float* __restrict__ b_sp)
{
    double xv[DI]; double sum = 0.0;
    for (int d = 0; d < DI; ++d) { xv[d] = (double)xrow[d]; sum += xv[d]; }
    const double mu = sum * (1.0 / (double)DI);
    double vs = 0.0;
    for (int d = 0; d < DI; ++d) { const double t = xv[d] - mu; vs += t * t; }
    const double rs = 1.0 / sqrt(vs * (1.0 / (double)DI) + 1e-5);
    double q[DI];
    for (int d = 0; d < DI; ++d)
        q[d] = (xv[d] - mu) * rs * (double)g_sp[d] + (double)b_sp[d];

    double best = -1e300; int bj = 0;
    for (int j = 0; j < BQ; ++j) {
        double a = 0.0;
        for (int d2 = 0; d2 < 7; ++d2) {
            const double2 kv = kp64[j * 7 + d2];
            a += q[2 * d2] * kv.x + q[2 * d2 + 1] * kv.y;
        }
        if (a > best) { best = a; bj = j; }
    }
    return bj;
}

__global__ __launch_bounds__(256) void hopfield_kernel(
    const float* __restrict__ x,
    const float* __restrict__ g_sp, const float* __restrict__ b_sp,
    const float* __restrict__ kf32, const float* __restrict__ Tf,
    const double2* __restrict__ kp64, const float* __restrict__ zbf,
    const float* __restrict__ Wb,
    float* __restrict__ out)
{
    __shared__ float ksh[BQ * 16];   // 16384 B, pattern-major, padded to 16 floats
    __shared__ float Ts[BQ * NC];    //  7168 B

    const int tid  = threadIdx.x;
    const int lane = tid & 63;
    const int w    = tid >> 6;

    {
        const float4* src = (const float4*)kf32;
        float4* dst = (float4*)ksh;
        for (int i = tid; i < BQ * 4; i += 256) dst[i] = src[i];
        for (int i = tid; i < BQ * NC; i += 256) Ts[i] = Tf[i];
    }
    __syncthreads();

    // Each lane owns 2 consecutive rows; wave covers 128 rows; block 512.
    const long rowBase = (long)blockIdx.x * 512 + (long)w * 128 + (long)lane * 2;

    // Load both x rows: 28 floats = 7 float4 (16B-aligned since rowBase even).
    float f[28];
    {
        const float4* xp = (const float4*)(x + rowBase * DI);
        float4* fv = (float4*)f;
        #pragma unroll
        for (int t = 0; t < 7; ++t) fv[t] = xp[t];
    }

    // fp32 LayerNorm per row.
    float q0[DI], q1[DI];
    {
        float s0 = 0.f, s1 = 0.f;
        #pragma unroll
        for (int d = 0; d < DI; ++d) { s0 += f[d]; s1 += f[DI + d]; }
        const float mu0 = s0 * (1.0f / DI), mu1 = s1 * (1.0f / DI);
        float v0 = 0.f, v1 = 0.f;
        #pragma unroll
        for (int d = 0; d < DI; ++d) {
            const float t0 = f[d] - mu0;      v0 += t0 * t0;
            const float t1 = f[DI + d] - mu1; v1 += t1 * t1;
        }
        const float rs0 = rsqrtf(v0 * (1.0f / DI) + 1e-5f);
        const float rs1 = rsqrtf(v1 * (1.0f / DI) + 1e-5f);
        #pragma unroll
        for (int d = 0; d < DI; ++d) {
            const float g = g_sp[d], bb_ = b_sp[d];
            q0[d] = (f[d] - mu0) * rs0 * g + bb_;
            q1[d] = (f[DI + d] - mu1) * rs1 * g + bb_;
        }
    }

    // Argmax over 256 patterns (k broadcast from LDS), tracking top-2 values.
    float best0 = -3e38f, sec0 = -3e38f, best1 = -3e38f, sec1 = -3e38f;
    int bj0 = 0, bj1 = 0;
    const float4* ksh4 = (const float4*)ksh;
    #pragma unroll 4
    for (int j = 0; j < BQ; ++j) {
        float kk[16];
        float4* kv = (float4*)kk;
        kv[0] = ksh4[4 * j + 0];
        kv[1] = ksh4[4 * j + 1];
        kv[2] = ksh4[4 * j + 2];
        kv[3] = ksh4[4 * j + 3];
        float a0 = 0.f, a1 = 0.f;
        #pragma unroll
        for (int d = 0; d < DI; ++d) {
            a0 = fmaf(q0[d], kk[d], a0);
            a1 = fmaf(q1[d], kk[d], a1);
        }
        {
            const bool c = a0 > best0;
            const float loser = c ? best0 : a0;   // min(a0, best0)
            sec0  = fmaxf(sec0, loser);
            best0 = c ? a0 : best0;
            bj0   = c ? j  : bj0;
        }
        {
            const bool c = a1 > best1;
            const float loser = c ? best1 : a1;
            sec1  = fmaxf(sec1, loser);
            best1 = c ? a1 : best1;
            bj1   = c ? j  : bj1;
        }
    }

    // Rare fp64 refine when the fp32 top-2 gap is inside the error margin.
    if (best0 - sec0 < MARGIN)
        bj0 = refine_row(x + rowBase * DI, kp64, g_sp, b_sp);
    if (best1 - sec1 < MARGIN)
        bj1 = refine_row(x + (rowBase + 1) * DI, kp64, g_sp, b_sp);

    // Head: z[b,c] = zb[c] + sum_s Wb[s] * T[jstar(b,s), c]; softmax over c.
    // Lanes L..L+7 (L = 8k) hold the 16 rows of one batch.
    const int s0 = (int)(rowBase & 15);
    const float wb0 = Wb[s0], wb1 = Wb[s0 + 1];
    float pz[NC];
    #pragma unroll
    for (int c = 0; c < NC; ++c)
        pz[c] = wb0 * Ts[bj0 * NC + c] + wb1 * Ts[bj1 * NC + c];
    #pragma unroll
    for (int m = 1; m < 8; m <<= 1) {
        #pragma unroll
        for (int c = 0; c < NC; ++c) pz[c] += __shfl_xor(pz[c], m);
    }
    if ((lane & 7) == 0) {
        const long batch = rowBase >> 4;
        float z[NC];
        float mx = -3e38f;
        #pragma unroll
        for (int c = 0; c < NC; ++c) { z[c] = pz[c] + zbf[c]; mx = fmaxf(mx, z[c]); }
        float den = 0.f;
        float e[NC];
        #pragma unroll
        for (int c = 0; c < NC; ++c) { e[c] = __expf(z[c] - mx); den += e[c]; }
        const float inv = 1.0f / den;
        #pragma unroll
        for (int c = 0; c < NC; ++c) out[batch * NC + c] = e[c] * inv;
    }
}

extern "C" void kernel_launch(void* const* d_in, const int* in_sizes, int n_in,
                              void* d_out, int out_size, void* d_ws, size_t ws_size,
                              hipStream_t stream) {
    const float* x      = (const float*)d_in[0];
    const float* lookup = (const float*)d_in[1];
    const float* g_st   = (const float*)d_in[2];
    const float* b_st   = (const float*)d_in[3];
    const float* g_sp   = (const float*)d_in[4];
    const float* b_sp   = (const float*)d_in[5];
    const float* g_pp   = (const float*)d_in[6];
    const float* b_pp   = (const float*)d_in[7];
    const float* Wv     = (const float*)d_in[8];
    const float* Wo     = (const float*)d_in[9];
    const float* Wm     = (const float*)d_in[10];
    const float* bm     = (const float*)d_in[11];
    const float* Wb     = (const float*)d_in[12];
    const float* bb     = (const float*)d_in[13];

    double2* kp64 = (double2*)((char*)d_ws + WS_KP64_OFF);
    float*   kf32 = (float*)((char*)d_ws + WS_KF32_OFF);
    float*   Tf   = (float*)((char*)d_ws + WS_TF_OFF);
    float*   zbf  = (float*)((char*)d_ws + WS_ZB_OFF);

    precompute_kernel<<<1, 256, 0, stream>>>(lookup, g_st, b_st, g_pp, b_pp,
                                             Wv, Wo, Wm, bm, Wb, bb,
                                             kp64, kf32, Tf, zbf);
    hopfield_kernel<<<BLOCKS, 256, 0, stream>>>(x, g_sp, b_sp, kf32, Tf, kp64,
                                                zbf, Wb, (float*)d_out);
}